// Round 10
// baseline (116.665 us; speedup 1.0000x reference)
//
#include <hip/hip_runtime.h>
#include <hip/hip_bf16.h>

#define N_NODES 20000
#define N_EDGES 2000
#define IN_FEATS 128
#define NUM_HEADS 4
#define OUT_FEATS 32
#define EDGE_DIM 64
#define C_FEATS 128   // NUM_HEADS*OUT_FEATS
#define NEG_SLOPE 0.2f
#define MAXD 256      // max pairs/edge bucket (mean 110, max~160, +14 sigma safe)
#define WT_LD 136     // padded LDS row (bf16 elems)
#define NTILES (N_NODES / 16)        // 1250 proj m-tiles
#define PROJ_BLKS ((NTILES + 3) / 4) // 313 proj blocks (4 waves each)
#define K1_BLK 512
#define K1_THR 256
#define CUR_STRIDE 16 // cursor padded to 1 counter / 64B line (atomic-serialization fix)
#define K23_BLK 1250  // merged edge+node kernel; must be <= co-resident capacity (5/CU w/ margin)
#define K23_THR 256

typedef __attribute__((ext_vector_type(8))) short bf16x8;
typedef __attribute__((ext_vector_type(4))) float f32x4;

__device__ __forceinline__ float leaky(float x) { return (x > 0.f) ? x : NEG_SLOPE * x; }
__device__ __forceinline__ unsigned short f2bf(float x) {
    __hip_bfloat16 h = __float2bfloat16(x);
    return *reinterpret_cast<unsigned short*>(&h);
}

// ---------------------------------------------------------------------------
// K1: blocks 0..PROJ_BLKS-1: MFMA projection; blocks PROJ_BLKS..511: bucket
// scatter + node_start build. (R7/R9 structure, unchanged.)
// ---------------------------------------------------------------------------
__global__ __launch_bounds__(K1_THR) void proj_scatter_kernel(
    const float* __restrict__ feat, const float* __restrict__ fc_w,
    const float* __restrict__ attn_src,
    const int* __restrict__ src_idx, const int* __restrict__ edge_idx, int P,
    __hip_bfloat16* __restrict__ feat_bf, float* __restrict__ s_buf,
    int* __restrict__ cursor, int* __restrict__ node_start, int* __restrict__ edge_nodes)
{
    __shared__ unsigned short Wt[128 * WT_LD];
    const int t = threadIdx.x;
    const int bid = blockIdx.x;

    if (bid < PROJ_BLKS) {
        for (int q = t; q < 64 * 128; q += K1_THR) {
            const int c = q & 127, k = (q >> 7) * 2;
            Wt[c * WT_LD + k]     = f2bf(fc_w[k * C_FEATS + c]);
            Wt[c * WT_LD + k + 1] = f2bf(fc_w[(k + 1) * C_FEATS + c]);
        }
        __syncthreads();

        const int wave = t >> 6, lane = t & 63;
        const int wid = bid * 4 + wave;
        if (wid < NTILES) {
            const int m0 = wid * 16;
            const int lrow = lane & 15, lk = lane >> 4;

            bf16x8 afr[4];
            const float* arow = feat + (size_t)(m0 + lrow) * IN_FEATS + lk * 8;
            #pragma unroll
            for (int kt = 0; kt < 4; ++kt) {
                const float4 f0 = *(const float4*)(arow + kt * 32);
                const float4 f1 = *(const float4*)(arow + kt * 32 + 4);
                bf16x8 a;
                a[0] = (short)f2bf(f0.x); a[1] = (short)f2bf(f0.y);
                a[2] = (short)f2bf(f0.z); a[3] = (short)f2bf(f0.w);
                a[4] = (short)f2bf(f1.x); a[5] = (short)f2bf(f1.y);
                a[6] = (short)f2bf(f1.z); a[7] = (short)f2bf(f1.w);
                afr[kt] = a;
            }

            f32x4 acc[8];
            #pragma unroll
            for (int nt = 0; nt < 8; ++nt) acc[nt] = (f32x4){0.f, 0.f, 0.f, 0.f};
            #pragma unroll
            for (int nt = 0; nt < 8; ++nt) {
                const unsigned short* wrow = &Wt[(nt * 16 + lrow) * WT_LD + lk * 8];
                #pragma unroll
                for (int kt = 0; kt < 4; ++kt) {
                    const bf16x8 b = *(const bf16x8*)(wrow + kt * 32);
                    acc[nt] = __builtin_amdgcn_mfma_f32_16x16x32_bf16(afr[kt], b, acc[nt], 0, 0, 0);
                }
            }

            // C layout: col = lane&15, row = (lane>>4)*4 + reg  (m89-verified)
            #pragma unroll
            for (int nt = 0; nt < 8; ++nt) {
                const int c = nt * 16 + lrow;
                #pragma unroll
                for (int r = 0; r < 4; ++r)
                    feat_bf[(size_t)(m0 + lk * 4 + r) * C_FEATS + c] = __float2bfloat16(acc[nt][r]);
            }
            float aw[8];
            #pragma unroll
            for (int nt = 0; nt < 8; ++nt) aw[nt] = attn_src[nt * 16 + lrow];
            #pragma unroll
            for (int h = 0; h < NUM_HEADS; ++h) {
                #pragma unroll
                for (int r = 0; r < 4; ++r) {
                    float v = acc[2 * h][r] * aw[2 * h] + acc[2 * h + 1][r] * aw[2 * h + 1];
                    v += __shfl_xor(v, 1);
                    v += __shfl_xor(v, 2);
                    v += __shfl_xor(v, 4);
                    v += __shfl_xor(v, 8);
                    if (lrow == 0) s_buf[(m0 + lk * 4 + r) * NUM_HEADS + h] = v;
                }
            }
        }
    } else {
        const int nthreads = (K1_BLK - PROJ_BLKS) * K1_THR;
        for (int p = (bid - PROJ_BLKS) * K1_THR + t; p < P; p += nthreads) {
            const int e = edge_idx[p];
            const int s = src_idx[p];
            const int pos = atomicAdd(&cursor[e * CUR_STRIDE], 1);
            if (pos < MAXD) edge_nodes[e * MAXD + pos] = s;
            const int prev = (p == 0) ? -1 : src_idx[p - 1];
            for (int n = prev + 1; n <= s; ++n) node_start[n] = p;
            if (p == P - 1)
                for (int n = s + 1; n <= N_NODES; ++n) node_start[n] = P;
        }
    }
}

// ---------------------------------------------------------------------------
// K23: merged edge-attention + disseminate with ONE fence-free grid barrier.
// Phase E (edges, grid-stride): R7-shaped softmax+aggregation; hef written as
// packed 2xbf16 u32 via DEVICE-SCOPE relaxed atomic stores (reach coherence
// point; no dirty L2 lines -> no wbL2 fence needed; mechanism = same one that
// makes the barrier counter itself work cross-XCD, R4/R5-proven).
// Barrier: vmcnt(0) drain -> monotone ticket (memset-zeroed, S=0) -> relaxed
// spin + s_sleep (R5 showed relaxed spin is benign; the FENCES were the 100us).
// Phase N (nodes, grid-stride): R9-shaped gather with PLAIN loads — L2 was
// invalidated at kernel launch by the CP, atomic stores left no stale lines,
// so first touch misses to fresh L3 data and then L2-caches normally.
// ---------------------------------------------------------------------------
union SharedU23 {
    struct {
        float4 w_sh[MAXD];
        int    n_sh[MAXD];
        float  te_sh[NUM_HEADS];
        float  inv_sh[NUM_HEADS];
        float  wred[4][NUM_HEADS];
        float  red[4][C_FEATS];
    } at;                              // phase E (~7.4 KB)
    struct {
        int e_sh[512];
        int ns_sh[9];
    } ds;                              // phase N (~2.1 KB)
};

__global__ __launch_bounds__(K23_THR, 5) void edge_node_kernel(
    const float* __restrict__ s_buf, const float* __restrict__ edge_feat,
    const float* __restrict__ attn_edge, const __hip_bfloat16* __restrict__ feat_bf,
    const int* __restrict__ cursor, const int* __restrict__ edge_nodes,
    const int* __restrict__ node_start, const int* __restrict__ edge_idx,
    unsigned* __restrict__ hef, unsigned* __restrict__ bar, float* __restrict__ out)
{
    __shared__ SharedU23 U;
    const int t = threadIdx.x;
    const int bid = blockIdx.x;
    const int wv = t >> 6, lane = t & 63;

    // ================= Phase E: per-edge softmax + aggregation =================
    for (int e = bid; e < N_EDGES; e += K23_BLK) {
        __syncthreads();   // guard LDS reuse across iterations

        if (t < EDGE_DIM) {
            const float v = edge_feat[e * EDGE_DIM + t];
            #pragma unroll
            for (int h = 0; h < NUM_HEADS; ++h) {
                float p = v * attn_edge[h * EDGE_DIM + t];
                p += __shfl_xor(p, 32); p += __shfl_xor(p, 16); p += __shfl_xor(p, 8);
                p += __shfl_xor(p, 4);  p += __shfl_xor(p, 2);  p += __shfl_xor(p, 1);
                if (t == 0) U.at.te_sh[h] = p;
            }
        }
        __syncthreads();

        const int m = min(cursor[e * CUR_STRIDE], MAXD);
        const int m_pad = (m + 31) & ~31;

        float ps0 = 0.f, ps1 = 0.f, ps2 = 0.f, ps3 = 0.f;
        if (t < m) {
            const int n = edge_nodes[e * MAXD + t];
            U.at.n_sh[t] = n;
            const float4 s4 = *(const float4*)&s_buf[n * NUM_HEADS];
            float4 w;
            w.x = __expf(leaky(s4.x + U.at.te_sh[0]));
            w.y = __expf(leaky(s4.y + U.at.te_sh[1]));
            w.z = __expf(leaky(s4.z + U.at.te_sh[2]));
            w.w = __expf(leaky(s4.w + U.at.te_sh[3]));
            U.at.w_sh[t] = w;
            ps0 = w.x; ps1 = w.y; ps2 = w.z; ps3 = w.w;
        } else if (t < m_pad) {
            U.at.n_sh[t] = 0;
            U.at.w_sh[t] = make_float4(0.f, 0.f, 0.f, 0.f);  // exact no-op in sums
        }
        #pragma unroll
        for (int d = 32; d >= 1; d >>= 1) {
            ps0 += __shfl_xor(ps0, d); ps1 += __shfl_xor(ps1, d);
            ps2 += __shfl_xor(ps2, d); ps3 += __shfl_xor(ps3, d);
        }
        if (lane == 0) {
            U.at.wred[wv][0] = ps0; U.at.wred[wv][1] = ps1;
            U.at.wred[wv][2] = ps2; U.at.wred[wv][3] = ps3;
        }
        __syncthreads();
        if (t < NUM_HEADS)
            U.at.inv_sh[t] = 1.f / (U.at.wred[0][t] + U.at.wred[1][t] +
                                    U.at.wred[2][t] + U.at.wred[3][t] + 1e-9f);
        __syncthreads();

        const int c0 = lane * 2;
        const int h = lane >> 4;
        float a0 = 0.f, a1 = 0.f;
        const unsigned short* fb = (const unsigned short*)feat_bf;
        #pragma unroll 8
        for (int j = wv; j < m_pad; j += 4) {
            const int n = U.at.n_sh[j];
            const float w = ((const float*)&U.at.w_sh[j])[h];
            const unsigned v = *(const unsigned*)(fb + (size_t)n * C_FEATS + c0);
            a0 += w * __uint_as_float(v << 16);
            a1 += w * __uint_as_float(v & 0xffff0000u);
        }
        U.at.red[wv][c0] = a0;
        U.at.red[wv][c0 + 1] = a1;
        __syncthreads();
        if (t < 64) {
            const float inv = U.at.inv_sh[t >> 4];
            const float r0 = (U.at.red[0][2 * t]     + U.at.red[1][2 * t] +
                              U.at.red[2][2 * t]     + U.at.red[3][2 * t]) * inv;
            const float r1 = (U.at.red[0][2 * t + 1] + U.at.red[1][2 * t + 1] +
                              U.at.red[2][2 * t + 1] + U.at.red[3][2 * t + 1]) * inv;
            const unsigned u = ((unsigned)f2bf(r1) << 16) | (unsigned)f2bf(r0);
            __hip_atomic_store(&hef[e * 64 + t], u, __ATOMIC_RELAXED, __HIP_MEMORY_SCOPE_AGENT);
        }
    }

    // ================= fence-free grid barrier =================
    asm volatile("s_waitcnt vmcnt(0)" ::: "memory");   // hef stores ack'd at coherence point
    __syncthreads();
    if (t == 0) {
        unsigned tk = __hip_atomic_fetch_add(bar, 1u, __ATOMIC_RELAXED, __HIP_MEMORY_SCOPE_AGENT);
        unsigned goal = (tk / K23_BLK + 1u) * K23_BLK;  // S=0 (memset) -> goal = K23_BLK
        while (__hip_atomic_load(bar, __ATOMIC_RELAXED, __HIP_MEMORY_SCOPE_AGENT) < goal)
            __builtin_amdgcn_s_sleep(8);
    }
    __syncthreads();
    asm volatile("" ::: "memory");                      // no compiler reordering past the spin

    // ================= Phase N: disseminate (8 nodes / group) =================
    for (int g = bid; g < N_NODES / 8; g += K23_BLK) {
        __syncthreads();   // guard LDS reuse
        if (t < 9) U.ds.ns_sh[t] = node_start[g * 8 + t];
        __syncthreads();
        const int s0 = U.ds.ns_sh[0], s1 = U.ds.ns_sh[8];
        const int c0 = lane * 2;

        float a00 = 0.f, a01 = 0.f, a10 = 0.f, a11 = 0.f;

        for (int cb = s0; cb < s1; cb += 512) {
            const int ccnt = min(512, s1 - cb);
            __syncthreads();
            for (int i = t; i < ccnt; i += K23_THR) U.ds.e_sh[i] = edge_idx[cb + i];
            __syncthreads();
            {
                const int jlo = max(U.ds.ns_sh[wv * 2], cb);
                const int jhi = min(U.ds.ns_sh[wv * 2 + 1], cb + ccnt);
                #pragma unroll 8
                for (int j = jlo; j < jhi; ++j) {
                    const unsigned v = hef[(size_t)U.ds.e_sh[j - cb] * 64 + lane];
                    a00 += __uint_as_float(v << 16);
                    a01 += __uint_as_float(v & 0xffff0000u);
                }
            }
            {
                const int jlo = max(U.ds.ns_sh[wv * 2 + 1], cb);
                const int jhi = min(U.ds.ns_sh[wv * 2 + 2], cb + ccnt);
                #pragma unroll 8
                for (int j = jlo; j < jhi; ++j) {
                    const unsigned v = hef[(size_t)U.ds.e_sh[j - cb] * 64 + lane];
                    a10 += __uint_as_float(v << 16);
                    a11 += __uint_as_float(v & 0xffff0000u);
                }
            }
        }
        const int n0 = g * 8;
        *(float2*)&out[(size_t)(n0 + wv * 2)     * C_FEATS + c0] = make_float2(a00, a01);
        *(float2*)&out[(size_t)(n0 + wv * 2 + 1) * C_FEATS + c0] = make_float2(a10, a11);
    }
}

extern "C" void kernel_launch(void* const* d_in, const int* in_sizes, int n_in,
                              void* d_out, int out_size, void* d_ws, size_t ws_size,
                              hipStream_t stream) {
    const float* feat      = (const float*)d_in[0];
    const float* edge_feat = (const float*)d_in[1];
    // d_in[2] = H (dense incidence) — intentionally unused
    const float* fc_w      = (const float*)d_in[3];
    const float* attn_src  = (const float*)d_in[4];
    const float* attn_edge = (const float*)d_in[5];
    const int*   src_idx   = (const int*)d_in[6];
    const int*   edge_idx  = (const int*)d_in[7];
    const int P = in_sizes[6];
    float* out = (float*)d_out;

    float* ws = (float*)d_ws;
    float*          s_buf      = ws;                                          // 20000*4 f32
    unsigned*       hef        = (unsigned*)(s_buf + N_NODES * NUM_HEADS);    // 2000*64 u32 (2xbf16)
    __hip_bfloat16* feat_bf    = (__hip_bfloat16*)(hef + N_EDGES * 64);       // 20000*128 bf16
    int*            node_start = (int*)(feat_bf + (size_t)N_NODES * C_FEATS); // 20001
    int*            edge_nodes = node_start + (N_NODES + 1);                  // 2000*MAXD
    int*            cursor     = edge_nodes + N_EDGES * MAXD;                 // 2000*CUR_STRIDE
    unsigned*       bar        = (unsigned*)(cursor + N_EDGES * CUR_STRIDE);  // 1 (+pad)

    // one memset node zeroes cursors + barrier counter (contiguous)
    hipMemsetAsync(cursor, 0, (N_EDGES * CUR_STRIDE) * sizeof(int) + 64, stream);
    proj_scatter_kernel<<<K1_BLK, K1_THR, 0, stream>>>(
        feat, fc_w, attn_src, src_idx, edge_idx, P,
        feat_bf, s_buf, cursor, node_start, edge_nodes);
    edge_node_kernel<<<K23_BLK, K23_THR, 0, stream>>>(
        s_buf, edge_feat, attn_edge, feat_bf, cursor, edge_nodes,
        node_start, edge_idx, hef, bar, out);
}

// Round 11
// 61.008 us; speedup vs baseline: 1.9123x; 1.9123x over previous
//
#include <hip/hip_runtime.h>
#include <hip/hip_bf16.h>

#define N_NODES 20000
#define N_EDGES 2000
#define IN_FEATS 128
#define NUM_HEADS 4
#define OUT_FEATS 32
#define EDGE_DIM 64
#define C_FEATS 128   // NUM_HEADS*OUT_FEATS
#define NEG_SLOPE 0.2f
#define MAXD 256      // max pairs/edge bucket (mean 110, max~160, +14 sigma safe)
#define WT_LD 136     // padded LDS row (bf16 elems)
#define NTILES (N_NODES / 16)        // 1250 proj m-tiles
#define PROJ_BLKS ((NTILES + 3) / 4) // 313 proj blocks (4 waves each)
#define K1_BLK 512
#define K1_THR 256
#define CUR_STRIDE 16 // cursor padded to 1 counter / 64B line (atomic-serialization fix)

typedef __attribute__((ext_vector_type(8))) short bf16x8;
typedef __attribute__((ext_vector_type(4))) float f32x4;
typedef __attribute__((ext_vector_type(2))) float f32x2;

__device__ __forceinline__ float leaky(float x) { return (x > 0.f) ? x : NEG_SLOPE * x; }
__device__ __forceinline__ unsigned short f2bf(float x) {
    __hip_bfloat16 h = __float2bfloat16(x);
    return *reinterpret_cast<unsigned short*>(&h);
}

// ---------------------------------------------------------------------------
// K1: blocks 0..PROJ_BLKS-1: MFMA projection; blocks PROJ_BLKS..511: bucket
// scatter + node_start build. All cross-kernel outputs written NON-TEMPORAL:
// stream to L3 during execution instead of a serialized dirty-L2 flush at the
// graph dependency boundary (R11 hypothesis for the ~25us overhead gap).
// ---------------------------------------------------------------------------
__global__ __launch_bounds__(K1_THR) void proj_scatter_kernel(
    const float* __restrict__ feat, const float* __restrict__ fc_w,
    const float* __restrict__ attn_src,
    const int* __restrict__ src_idx, const int* __restrict__ edge_idx, int P,
    unsigned short* __restrict__ feat_bf, float* __restrict__ s_buf,
    int* __restrict__ cursor, int* __restrict__ node_start, int* __restrict__ edge_nodes)
{
    __shared__ unsigned short Wt[128 * WT_LD];
    const int t = threadIdx.x;
    const int bid = blockIdx.x;

    if (bid < PROJ_BLKS) {
        for (int q = t; q < 64 * 128; q += K1_THR) {
            const int c = q & 127, k = (q >> 7) * 2;
            Wt[c * WT_LD + k]     = f2bf(fc_w[k * C_FEATS + c]);
            Wt[c * WT_LD + k + 1] = f2bf(fc_w[(k + 1) * C_FEATS + c]);
        }
        __syncthreads();

        const int wave = t >> 6, lane = t & 63;
        const int wid = bid * 4 + wave;
        if (wid < NTILES) {
            const int m0 = wid * 16;
            const int lrow = lane & 15, lk = lane >> 4;

            bf16x8 afr[4];
            const float* arow = feat + (size_t)(m0 + lrow) * IN_FEATS + lk * 8;
            #pragma unroll
            for (int kt = 0; kt < 4; ++kt) {
                const float4 f0 = *(const float4*)(arow + kt * 32);
                const float4 f1 = *(const float4*)(arow + kt * 32 + 4);
                bf16x8 a;
                a[0] = (short)f2bf(f0.x); a[1] = (short)f2bf(f0.y);
                a[2] = (short)f2bf(f0.z); a[3] = (short)f2bf(f0.w);
                a[4] = (short)f2bf(f1.x); a[5] = (short)f2bf(f1.y);
                a[6] = (short)f2bf(f1.z); a[7] = (short)f2bf(f1.w);
                afr[kt] = a;
            }

            f32x4 acc[8];
            #pragma unroll
            for (int nt = 0; nt < 8; ++nt) acc[nt] = (f32x4){0.f, 0.f, 0.f, 0.f};
            #pragma unroll
            for (int nt = 0; nt < 8; ++nt) {
                const unsigned short* wrow = &Wt[(nt * 16 + lrow) * WT_LD + lk * 8];
                #pragma unroll
                for (int kt = 0; kt < 4; ++kt) {
                    const bf16x8 b = *(const bf16x8*)(wrow + kt * 32);
                    acc[nt] = __builtin_amdgcn_mfma_f32_16x16x32_bf16(afr[kt], b, acc[nt], 0, 0, 0);
                }
            }

            // C layout: col = lane&15, row = (lane>>4)*4 + reg  (m89-verified)
            #pragma unroll
            for (int nt = 0; nt < 8; ++nt) {
                const int c = nt * 16 + lrow;
                #pragma unroll
                for (int r = 0; r < 4; ++r)
                    __builtin_nontemporal_store(
                        f2bf(acc[nt][r]),
                        &feat_bf[(size_t)(m0 + lk * 4 + r) * C_FEATS + c]);
            }
            float aw[8];
            #pragma unroll
            for (int nt = 0; nt < 8; ++nt) aw[nt] = attn_src[nt * 16 + lrow];
            #pragma unroll
            for (int h = 0; h < NUM_HEADS; ++h) {
                #pragma unroll
                for (int r = 0; r < 4; ++r) {
                    float v = acc[2 * h][r] * aw[2 * h] + acc[2 * h + 1][r] * aw[2 * h + 1];
                    v += __shfl_xor(v, 1);
                    v += __shfl_xor(v, 2);
                    v += __shfl_xor(v, 4);
                    v += __shfl_xor(v, 8);
                    if (lrow == 0)
                        __builtin_nontemporal_store(v, &s_buf[(m0 + lk * 4 + r) * NUM_HEADS + h]);
                }
            }
        }
    } else {
        const int nthreads = (K1_BLK - PROJ_BLKS) * K1_THR;
        for (int p = (bid - PROJ_BLKS) * K1_THR + t; p < P; p += nthreads) {
            const int e = edge_idx[p];
            const int s = src_idx[p];
            const int pos = atomicAdd(&cursor[e * CUR_STRIDE], 1);
            if (pos < MAXD) __builtin_nontemporal_store(s, &edge_nodes[e * MAXD + pos]);
            const int prev = (p == 0) ? -1 : src_idx[p - 1];
            for (int n = prev + 1; n <= s; ++n)
                __builtin_nontemporal_store(p, &node_start[n]);
            if (p == P - 1)
                for (int n = s + 1; n <= N_NODES; ++n)
                    __builtin_nontemporal_store(P, &node_start[n]);
        }
    }
}

// ---------------------------------------------------------------------------
// K2: per-edge softmax + aggregation. Block = 1 edge (2000 blocks), 512 threads
// = 8 wave-substreams. Max-free softmax; staging padded to x32 with w=0 so the
// aggregation loop is branch-free. hef written bf16 with NORMAL stores (K3
// re-reads each row ~11x -> wants it L2-resident; only 512KB dirty).
// ---------------------------------------------------------------------------
__global__ __launch_bounds__(512) void edge_attn_kernel(
    const float* __restrict__ s_buf, const float* __restrict__ edge_feat,
    const float* __restrict__ attn_edge, const unsigned short* __restrict__ feat_bf,
    const int* __restrict__ cursor, const int* __restrict__ edge_nodes,
    __hip_bfloat16* __restrict__ hef)
{
    __shared__ float4 w_sh[MAXD];
    __shared__ int    n_sh[MAXD];
    __shared__ float  te_sh[NUM_HEADS];
    __shared__ float  inv_sh[NUM_HEADS];
    __shared__ float  wred[8][NUM_HEADS];
    __shared__ float  red[8][C_FEATS];

    const int e = blockIdx.x;
    const int t = threadIdx.x;
    const int wv = t >> 6, lane = t & 63;

    // fused edge projection te[h] = <edge_feat[e,:], attn_edge[h,:]> (wave 0)
    if (t < EDGE_DIM) {
        const float v = edge_feat[e * EDGE_DIM + t];
        #pragma unroll
        for (int h = 0; h < NUM_HEADS; ++h) {
            float p = v * attn_edge[h * EDGE_DIM + t];
            p += __shfl_xor(p, 32); p += __shfl_xor(p, 16); p += __shfl_xor(p, 8);
            p += __shfl_xor(p, 4);  p += __shfl_xor(p, 2);  p += __shfl_xor(p, 1);
            if (t == 0) te_sh[h] = p;
        }
    }
    __syncthreads();

    const int m = min(cursor[e * CUR_STRIDE], MAXD);
    const int m_pad = (m + 31) & ~31;

    float ps0 = 0.f, ps1 = 0.f, ps2 = 0.f, ps3 = 0.f;
    if (t < m) {
        const int n = edge_nodes[e * MAXD + t];
        n_sh[t] = n;
        const float4 s4 = *(const float4*)&s_buf[n * NUM_HEADS];
        float4 w;
        w.x = __expf(leaky(s4.x + te_sh[0]));
        w.y = __expf(leaky(s4.y + te_sh[1]));
        w.z = __expf(leaky(s4.z + te_sh[2]));
        w.w = __expf(leaky(s4.w + te_sh[3]));
        w_sh[t] = w;
        ps0 = w.x; ps1 = w.y; ps2 = w.z; ps3 = w.w;
    } else if (t < m_pad) {
        n_sh[t] = 0;
        w_sh[t] = make_float4(0.f, 0.f, 0.f, 0.f);   // exact no-op in all sums
    }
    #pragma unroll
    for (int d = 32; d >= 1; d >>= 1) {
        ps0 += __shfl_xor(ps0, d); ps1 += __shfl_xor(ps1, d);
        ps2 += __shfl_xor(ps2, d); ps3 += __shfl_xor(ps3, d);
    }
    if (lane == 0) {
        wred[wv][0] = ps0; wred[wv][1] = ps1; wred[wv][2] = ps2; wred[wv][3] = ps3;
    }
    __syncthreads();
    if (t < NUM_HEADS) {
        float s = 0.f;
        #pragma unroll
        for (int w8 = 0; w8 < 8; ++w8) s += wred[w8][t];
        inv_sh[t] = 1.f / (s + 1e-9f);
    }
    __syncthreads();

    // aggregation: substream wv (0..7) handles j = wv, wv+8, ...; branch-free
    const int c0 = lane * 2;
    const int h = lane >> 4;
    float a0 = 0.f, a1 = 0.f;
    #pragma unroll 8
    for (int j = wv; j < m_pad; j += 8) {
        const int n = n_sh[j];
        const float w = ((const float*)&w_sh[j])[h];
        const unsigned v = *(const unsigned*)(feat_bf + (size_t)n * C_FEATS + c0);
        a0 += w * __uint_as_float(v << 16);
        a1 += w * __uint_as_float(v & 0xffff0000u);
    }
    red[wv][c0] = a0;
    red[wv][c0 + 1] = a1;
    __syncthreads();
    if (t < C_FEATS) {
        float r = 0.f;
        #pragma unroll
        for (int w8 = 0; w8 < 8; ++w8) r += red[w8][t];
        hef[e * C_FEATS + t] = __float2bfloat16(r * inv_sh[t >> 5]);
    }
}

// ---------------------------------------------------------------------------
// K3: disseminate. 2500 blocks x 8 nodes, 256 threads = 4 waves; each wave
// owns 2 nodes, each lane 2 bf16 channels -> one wave load = one full 256B
// hef row. out written NON-TEMPORAL (10MB, read only by host after sync).
// ---------------------------------------------------------------------------
#define K3_NODES 8
#define K3_CHUNK 512
__global__ __launch_bounds__(256) void disseminate_kernel(
    const int* __restrict__ node_start, const int* __restrict__ edge_idx,
    const __hip_bfloat16* __restrict__ hef, float* __restrict__ out)
{
    __shared__ int e_sh[K3_CHUNK];
    __shared__ int ns_sh[K3_NODES + 1];
    const int t = threadIdx.x;
    const int wv = t >> 6, lane = t & 63;
    const int c0 = lane * 2;
    const int n0 = blockIdx.x * K3_NODES;

    if (t < K3_NODES + 1) ns_sh[t] = node_start[n0 + t];
    __syncthreads();
    const int s0 = ns_sh[0], s1 = ns_sh[K3_NODES];

    float a00 = 0.f, a01 = 0.f, a10 = 0.f, a11 = 0.f;  // [node r][chan 0/1]
    const unsigned short* hu = (const unsigned short*)hef;

    for (int cb = s0; cb < s1; cb += K3_CHUNK) {
        const int ccnt = min(K3_CHUNK, s1 - cb);
        __syncthreads();
        for (int i = t; i < ccnt; i += 256) e_sh[i] = edge_idx[cb + i];
        __syncthreads();
        {
            const int jlo = max(ns_sh[wv * 2], cb);
            const int jhi = min(ns_sh[wv * 2 + 1], cb + ccnt);
            #pragma unroll 8
            for (int j = jlo; j < jhi; ++j) {
                const unsigned v = *(const unsigned*)(hu + (size_t)e_sh[j - cb] * C_FEATS + c0);
                a00 += __uint_as_float(v << 16);
                a01 += __uint_as_float(v & 0xffff0000u);
            }
        }
        {
            const int jlo = max(ns_sh[wv * 2 + 1], cb);
            const int jhi = min(ns_sh[wv * 2 + 2], cb + ccnt);
            #pragma unroll 8
            for (int j = jlo; j < jhi; ++j) {
                const unsigned v = *(const unsigned*)(hu + (size_t)e_sh[j - cb] * C_FEATS + c0);
                a10 += __uint_as_float(v << 16);
                a11 += __uint_as_float(v & 0xffff0000u);
            }
        }
    }
    const f32x2 r0 = {a00, a01};
    const f32x2 r1 = {a10, a11};
    __builtin_nontemporal_store(r0, (f32x2*)&out[(size_t)(n0 + wv * 2)     * C_FEATS + c0]);
    __builtin_nontemporal_store(r1, (f32x2*)&out[(size_t)(n0 + wv * 2 + 1) * C_FEATS + c0]);
}

extern "C" void kernel_launch(void* const* d_in, const int* in_sizes, int n_in,
                              void* d_out, int out_size, void* d_ws, size_t ws_size,
                              hipStream_t stream) {
    const float* feat      = (const float*)d_in[0];
    const float* edge_feat = (const float*)d_in[1];
    // d_in[2] = H (dense incidence) — intentionally unused
    const float* fc_w      = (const float*)d_in[3];
    const float* attn_src  = (const float*)d_in[4];
    const float* attn_edge = (const float*)d_in[5];
    const int*   src_idx   = (const int*)d_in[6];
    const int*   edge_idx  = (const int*)d_in[7];
    const int P = in_sizes[6];
    float* out = (float*)d_out;

    float* ws = (float*)d_ws;
    float*          s_buf      = ws;                                          // 20000*4 f32
    __hip_bfloat16* hef        = (__hip_bfloat16*)(s_buf + N_NODES * NUM_HEADS); // 2000*128 bf16
    unsigned short* feat_bf    = (unsigned short*)(hef + N_EDGES * C_FEATS);  // 20000*128 bf16
    int*            node_start = (int*)(feat_bf + (size_t)N_NODES * C_FEATS); // 20001
    int*            edge_nodes = node_start + (N_NODES + 1);                  // 2000*MAXD
    int*            cursor     = edge_nodes + N_EDGES * MAXD;                 // 2000*CUR_STRIDE

    hipMemsetAsync(cursor, 0, N_EDGES * CUR_STRIDE * sizeof(int), stream);
    proj_scatter_kernel<<<K1_BLK, K1_THR, 0, stream>>>(
        feat, fc_w, attn_src, src_idx, edge_idx, P,
        feat_bf, s_buf, cursor, node_start, edge_nodes);
    edge_attn_kernel<<<N_EDGES, 512, 0, stream>>>(
        s_buf, edge_feat, attn_edge, feat_bf, cursor, edge_nodes, hef);
    disseminate_kernel<<<N_NODES / K3_NODES, 256, 0, stream>>>(
        node_start, edge_idx, hef, out);
}